// Round 5
// baseline (781.461 us; speedup 1.0000x reference)
//
#include <hip/hip_runtime.h>

// ---------------------------------------------------------------------------
// 2-layer LSTM (H=51) + Linear(51,1), B=1024, T=1024, fp32.
// R18 = R17 with fused-rcp activations + guard stripping.
//   Post-mortem R17: step = 1675cy; VALU issue/SIMD ~854cy (51%) matches
//   VALUBusy 60% (active-CU). Trans = 20/lane-step x 8cy = 160 of 244cy
//   per wave-step -> dominant. Occupancy & wave levers exhausted.
//   - Fused activations (algebraically identical, 20 -> 16 trans):
//       i*g = (E-1)*rcp((1+e_i)(E+1))      [one rcp for i and g]
//       h   = (Ec-1)*rcp((Ec+1)(1+e_o))    [one rcp for o and tanh(c)]
//   - Unconditional h-stores: u=4t+q <= 51 for t<=12; row 51 gets exact 0
//     (bb=0 there) and is masked by zero A-frag columns / wl[51]=0.
//   - k=0/k=1 peeled: steady loop has no k!=0 / k>=2 compares.
//   - Rest R17-proven: fp16 single-term MFMA (6/wave-step), 4x ds_read_b128,
//     exp2-domain gates (W/bias pre-scaled by log2e / 2log2e), bias+Wx in
//     MFMA acc init, unroll x2 (rb/wbuf literal), 14 waves (13 tile + 1 y),
//     waves_per_eu(4,4), prow=4u+g lane-local acts, plane stride 88 (176B)
//     conflict-free b128, ONE barrier/step, L2 one step behind L1,
//     ping-pong buffers, deferred y(k-2) on wave 13.
// ---------------------------------------------------------------------------

#define H     51
#define NROW  204      // 4*H
#define TLEN  1024
#define BPB   16       // batches per block (= mfma N)
#define NTHR  896      // 14 waves
#define NBLK  64
#define KPAD  88       // fp16 row stride (176B) -> conflict-free b128 reads

#define LOG2E  1.442695041f
#define LOG2E2 2.885390082f

typedef __attribute__((ext_vector_type(8))) _Float16 half8;  // 8 f16 = 4 VGPRs
typedef __attribute__((ext_vector_type(4))) float f4;

__device__ __forceinline__ float frcp(float x) { return __builtin_amdgcn_rcpf(x); }
#if __has_builtin(__builtin_amdgcn_exp2f)
__device__ __forceinline__ float ex2(float x) { return __builtin_amdgcn_exp2f(x); }
#else
__device__ __forceinline__ float ex2(float x) { return __expf(x * 0.6931471806f); }
#endif

__device__ __forceinline__ half8 lds8h(const _Float16* p) {  // one ds_read_b128
    return *(const half8*)__builtin_assume_aligned(p, 16);
}

#define MFMA(ACC, A, B) \
    ACC = __builtin_amdgcn_mfma_f32_16x16x32_f16((A), (B), (ACC), 0, 0, 0)

// A-frag for 16x16x32: lane holds A[m=lane&15][k=quad*8+j], j=0..7.
// Source W is [204][51] row-major, PyTorch rows g*51+u; permuted row
// prow = 4u+g -> src row = (prow&3)*51 + (prow>>2). Zero-pad prow>=204, k>=51.
// Rows pre-scaled by log2e (2*log2e for tanh gate g==2) for exp2-domain acts.
__device__ __forceinline__ half8 load_wfrag(const float* __restrict__ W,
                                            int tile, int kt, int q, int mcol)
{
    half8 hf;
    const int prow = tile * 16 + mcol;
    const float sc = ((prow & 3) == 2) ? LOG2E2 : LOG2E;
#pragma unroll
    for (int j = 0; j < 8; ++j) {
        const int kk = kt * 32 + q * 8 + j;
        float v = 0.0f;
        if (prow < NROW && kk < H) {
            const int srow = (prow & 3) * H + (prow >> 2);
            v = W[srow * H + kk];
        }
        hf[j] = (_Float16)(v * sc);
    }
    return hf;
}

// Fused LSTM cell update (exp2-domain gate pre-activations a_i,a_f,b_g,d_o):
//   c' = sigm(a_f)*c + sigm(a_i)*tanh-half(b_g)
//      = c*rcp(1+e_f) + (Eg-1)*rcp((1+e_i)(Eg+1))
//   h' = sigm(d_o)*tanh(c') = (Ec-1)*rcp((Ec+1)(1+e_o))
// 5 ex2 + 3 rcp = 8 trans (was 10). Algebraically identical to unfused.
__device__ __forceinline__ float cell(float a_i, float a_f, float b_g,
                                      float d_o, float* c)
{
    const float e_i = ex2(-a_i);
    const float e_f = ex2(-a_f);
    const float Eg  = ex2(b_g);
    const float f   = frcp(1.0f + e_f);
    const float ig  = (Eg - 1.0f) * frcp((1.0f + e_i) * (Eg + 1.0f));
    const float cn  = fmaf(f, *c, ig);
    *c = cn;
    const float Ec  = ex2(cn * LOG2E2);
    const float e_o = ex2(-d_o);
    return (Ec - 1.0f) * frcp((Ec + 1.0f) * (1.0f + e_o));
}

__global__
__attribute__((amdgpu_flat_work_group_size(NTHR, NTHR), amdgpu_waves_per_eu(4, 4)))
void lstm2_kernel(const float* __restrict__ input,
                  const float* __restrict__ W_ih1, const float* __restrict__ W_hh1,
                  const float* __restrict__ b_ih1, const float* __restrict__ b_hh1,
                  const float* __restrict__ W_ih2, const float* __restrict__ W_hh2,
                  const float* __restrict__ b_ih2, const float* __restrict__ b_hh2,
                  const float* __restrict__ W_lin, const float* __restrict__ b_lin,
                  float* __restrict__ out)
{
    const int tid  = threadIdx.x;
    const int w    = tid >> 6;        // wave 0..13
    const int lane = tid & 63;
    const int q    = lane >> 4;       // quad
    const int mcol = lane & 15;       // batch column (and A-frag m)
    const int b0   = blockIdx.x * BPB;

    const bool tile_wave = (w < 13);
    const bool y_wave    = (w == 13);

    // [buf][plane][mcol][k]; planes: 0=h1 1=h2 (fp16).
    // Rows k in [52,88) stay zero (init below, never written); row 51 is
    // written each step but always exactly 0 (bb=0 for u=51 -> h=0).
    __shared__ __align__(16) _Float16 hb[2][2][BPB][KPAD];

    {
        _Float16* hz = &hb[0][0][0][0];
        for (int i = tid; i < 2 * 2 * BPB * KPAD; i += NTHR) hz[i] = (_Float16)0.0f;
    }

    // ---- persistent weight fragments: wave w owns tile w ------------------
    half8 A1[2], Ai[2], Ah[2];            // W_hh1 / W_ih2 / W_hh2, x Ktile
    f4 bb1, bb2, wxv;
    float c1 = 0.0f, c2 = 0.0f;
    const int t = w;                      // tile
    const int u = 4 * t + q;              // this lane's unit (<= 51 for t<13)

    if (tile_wave) {
#pragma unroll
        for (int kt = 0; kt < 2; ++kt) {
            A1[kt] = load_wfrag(W_hh1, t, kt, q, mcol);
            Ai[kt] = load_wfrag(W_ih2, t, kt, q, mcol);
            Ah[kt] = load_wfrag(W_hh2, t, kt, q, mcol);
        }
#pragma unroll
        for (int j = 0; j < 4; ++j) {     // gate j of unit u (PyTorch row j*H+u)
            const bool v = (u < H);
            const float sc = (j == 2) ? LOG2E2 : LOG2E;
            bb1[j] = v ? sc * (b_ih1[j * H + u] + b_hh1[j * H + u]) : 0.0f;
            bb2[j] = v ? sc * (b_ih2[j * H + u] + b_hh2[j * H + u]) : 0.0f;
            wxv[j] = v ? sc * W_ih1[j * H + u] : 0.0f;
        }
    }

    float wl[16];                          // wave13: y-dot weights, rows q*16+i
    if (y_wave) {
#pragma unroll
        for (int i = 0; i < 16; ++i) {
            const int r = q * 16 + i;
            wl[i] = (r < H) ? W_lin[r] : 0.0f;
        }
    }
    const float blin = b_lin[0];

    float xcur = input[(size_t)(b0 + mcol) * TLEN + 0];

    __syncthreads();                       // zeros visible

// One LSTM step: reads buf RB (h1(k-1), h2(k-2)), writes buf WB.
// RB/WB/L2EN/YEN are literals -> guards fold, LDS addresses loop-invariant.
#define STEP(KK, RB, WB, L2EN, YEN)                                            \
do {                                                                           \
    const int k_  = (KK);                                                      \
    const int kn_ = (k_ + 1 < TLEN) ? (k_ + 1) : (TLEN - 1);                   \
    const float xnext_ = input[(size_t)(b0 + mcol) * TLEN + kn_];              \
    if (tile_wave) {                                                           \
        half8 B1a = lds8h(&hb[RB][0][mcol][q * 8]);                            \
        half8 B1b = lds8h(&hb[RB][0][mcol][32 + q * 8]);                       \
        f4 g1;                                                                 \
        g1[0] = fmaf(wxv[0], xcur, bb1[0]);                                    \
        g1[1] = fmaf(wxv[1], xcur, bb1[1]);                                    \
        g1[2] = fmaf(wxv[2], xcur, bb1[2]);                                    \
        g1[3] = fmaf(wxv[3], xcur, bb1[3]);                                    \
        MFMA(g1, A1[0], B1a);  MFMA(g1, A1[1], B1b);                           \
        /* L1 acts (step k) */                                                 \
        const float h1n = cell(g1[0], g1[1], g1[2], g1[3], &c1);               \
        hb[WB][0][mcol][u] = (_Float16)h1n;                                    \
        if (L2EN) {                                                            \
            half8 B2a = lds8h(&hb[RB][1][mcol][q * 8]);                        \
            half8 B2b = lds8h(&hb[RB][1][mcol][32 + q * 8]);                   \
            f4 g2 = bb2;                                                       \
            MFMA(g2, Ai[0], B1a);  MFMA(g2, Ai[1], B1b);                       \
            MFMA(g2, Ah[0], B2a);  MFMA(g2, Ah[1], B2b);                       \
            /* L2 acts (step k-1) */                                           \
            const float h2n = cell(g2[0], g2[1], g2[2], g2[3], &c2);           \
            hb[WB][1][mcol][u] = (_Float16)h2n;                                \
        }                                                                      \
    } else if (y_wave && (YEN)) {                                              \
        /* deferred y(k-2) from h2 plane of buf RB (stable this iter) */       \
        half8 y0 = lds8h(&hb[RB][1][mcol][q * 16]);                            \
        half8 y1 = lds8h(&hb[RB][1][mcol][q * 16 + 8]);                        \
        float yp = 0.0f;                                                       \
        _Pragma("unroll")                                                      \
        for (int i = 0; i < 8; ++i) {                                          \
            yp += wl[i]     * (float)y0[i];                                    \
            yp += wl[i + 8] * (float)y1[i];                                    \
        }                                                                      \
        yp += __shfl_xor(yp, 16);                                              \
        yp += __shfl_xor(yp, 32);                                              \
        if (q == 0) out[(size_t)(b0 + mcol) * TLEN + (k_ - 2)] = yp + blin;    \
    }                                                                          \
    __syncthreads();                                                           \
    xcur = xnext_;                                                             \
} while (0)

    // k even: rb=1, wbuf=0; k odd: rb=0, wbuf=1.
    STEP(0, 1, 0, 0, 0);                   // L1 only (h2(-1) stays 0)
    STEP(1, 0, 1, 1, 0);                   // +L2 (step 0); y starts at k=2
    for (int k = 2; k < TLEN; k += 2) {    // steady: no guards
        STEP(k, 1, 0, 1, 1);
        STEP(k + 1, 0, 1, 1, 1);
    }
    STEP(TLEN, 1, 0, 1, 1);                // tail: L2(step 1023) + y(1022)
#undef STEP

    // epilogue: y(T-1) from h2 plane of buf (TLEN & 1) = 0 (= wbuf at k=TLEN)
    if (y_wave) {
        half8 y0 = lds8h(&hb[0][1][mcol][q * 16]);
        half8 y1 = lds8h(&hb[0][1][mcol][q * 16 + 8]);
        float yp = 0.0f;
#pragma unroll
        for (int i = 0; i < 8; ++i) {
            yp += wl[i]     * (float)y0[i];
            yp += wl[i + 8] * (float)y1[i];
        }
        yp += __shfl_xor(yp, 16);
        yp += __shfl_xor(yp, 32);
        if (q == 0) out[(size_t)(b0 + mcol) * TLEN + (TLEN - 1)] = yp + blin;
    }
}

extern "C" void kernel_launch(void* const* d_in, const int* in_sizes, int n_in,
                              void* d_out, int out_size, void* d_ws, size_t ws_size,
                              hipStream_t stream)
{
    const float* input = (const float*)d_in[0];
    const float* W_ih1 = (const float*)d_in[1];
    const float* W_hh1 = (const float*)d_in[2];
    const float* b_ih1 = (const float*)d_in[3];
    const float* b_hh1 = (const float*)d_in[4];
    const float* W_ih2 = (const float*)d_in[5];
    const float* W_hh2 = (const float*)d_in[6];
    const float* b_ih2 = (const float*)d_in[7];
    const float* b_hh2 = (const float*)d_in[8];
    const float* W_lin = (const float*)d_in[9];
    const float* b_lin = (const float*)d_in[10];

    float* out = (float*)d_out;

    hipLaunchKernelGGL(lstm2_kernel, dim3(NBLK), dim3(NTHR), 0, stream,
                       input, W_ih1, W_hh1, b_ih1, b_hh1,
                       W_ih2, W_hh2, b_ih2, b_hh2, W_lin, b_lin,
                       out);
}